// Round 9
// baseline (213.517 us; speedup 1.0000x reference)
//
#include <hip/hip_runtime.h>
#include <hip/hip_bf16.h>

// MultiHeadMALAAttention: B=4 N=8192 DIM=256 H=8 HD=32 INTERNAL=256
// Dtypes: inputs fp32, output fp32; intermediates bf16; compute fp32.
// R9: bisect after R8's post-timing divergence. Exactly R7 + BK=64 (single
// delta from proven config). XOR swizzle REMOVED (prime suspect for the
// nondeterministic staging corruption), cvt back to 3 launches.
// ws (~81 MB): [0,4K) ksum | [4K,8K) vsum | [8K,136K) kvT | 256K: kh_t vv oo
// qh xbf (16MB each) | Wqb | Wpb. resf aliases xbf (dead after gemm1).

typedef __bf16 bf16x8 __attribute__((ext_vector_type(8)));
typedef float  f32x4  __attribute__((ext_vector_type(4)));
typedef float  f32x2  __attribute__((ext_vector_type(2)));

#define NSEQ  8192
#define TOK   32768
#define SCALE_F 0.17677669529663687f        // 32^-0.5
#define S2_F    2.1579674718339462e-05f     // SCALE/NSEQ

__device__ __forceinline__ void gld16(void* lds, const void* g) {
  __builtin_amdgcn_global_load_lds((const __attribute__((address_space(1))) void*)g,
                                   (__attribute__((address_space(3))) void*)lds,
                                   16, 0, 0);
}

__device__ __forceinline__ bf16x8 cvt8(const float* p) {
  f32x4 a = *(const f32x4*)p;
  f32x4 b = *(const f32x4*)(p + 4);
  bf16x8 r;
  r[0]=(__bf16)a.x; r[1]=(__bf16)a.y; r[2]=(__bf16)a.z; r[3]=(__bf16)a.w;
  r[4]=(__bf16)b.x; r[5]=(__bf16)b.y; r[6]=(__bf16)b.z; r[7]=(__bf16)b.w;
  return r;
}

// ---------------- cvt: fp32 -> bf16, 8 elems/thread --------------------------
__global__ __launch_bounds__(256)
void cvt_kernel(const float* __restrict__ src, __bf16* __restrict__ dst, int n8)
{
  const int i = blockIdx.x*256 + threadIdx.x;
  if (i >= n8) return;
  *(bf16x8*)(dst + (long)i*8) = cvt8(src + (long)i*8);
}

// ---------------- GEMM: C[M x Nn] = A[M x K] * B[Nn x K]^T, K=256 ------------
// 128x128 tile, BK=64, global_load_lds(16B) staging (NO swizzle — R7-proven
// addressing), 4 waves, each wave 4x4 16x16x32 MFMA tiles (2 k-steps/iter).
// EPI=1: o0=qh, o1=kh_t (HEAD-major), o2=vv, o3=oo (bias+elu+1 on q,k).
// EPI=2: o0=out (TO=float), bias only.
template<int EPI, typename TO>
__global__ __launch_bounds__(256)
void gemm_kernel(const __bf16* __restrict__ A, const __bf16* __restrict__ Bw,
                 const float* __restrict__ bias,
                 TO* __restrict__ o0, __bf16* __restrict__ o1,
                 __bf16* __restrict__ o2, __bf16* __restrict__ o3)
{
  constexpr int K = 256;
  __shared__ __align__(16) __bf16 As[128*64];   // 16 KB
  __shared__ __align__(16) __bf16 Bs[128*64];   // 16 KB
  const int tid  = threadIdx.x;
  const int lane = tid & 63;
  const int wid  = tid >> 6;
  const int wm = wid & 1, wn = wid >> 1;
  const long m0 = (long)blockIdx.x * 128;
  const int  n0 = blockIdx.y * 128;

  const int srow = tid >> 3;                 // 0..31 (staging row within call)
  const int scol = tid & 7;                  // col8 slot (identity mapping)
  const __bf16* ag = A  + (m0 + srow)*K + scol*8;
  const __bf16* bg = Bw + (long)(n0 + srow)*K + scol*8;
  __bf16* asw = As + tid*8;                  // lane-contig 16B (gld16 dst rule)
  __bf16* bsw = Bs + tid*8;

  f32x4 acc[4][4] = {};

  for (int k0 = 0; k0 < K; k0 += 64) {
    __syncthreads();                       // prior iter's ds_reads complete
#pragma unroll
    for (int q = 0; q < 4; q++) {          // call q covers rows q*32..q*32+31
      gld16(asw + q*2048, ag + (long)q*32*K + k0);
      gld16(bsw + q*2048, bg + (long)q*32*K + k0);
    }
    __syncthreads();                       // staging visible (vmcnt drain)
    const int row = lane & 15;
    const int k8  = lane >> 4;             // 0..3
#pragma unroll
    for (int ks = 0; ks < 2; ks++) {
      bf16x8 af[4], bfr[4];
#pragma unroll
      for (int i=0;i<4;i++)
        af[i] = *(const bf16x8*)&As[(wm*64 + i*16 + row)*64 + (ks*4 + k8)*8];
#pragma unroll
      for (int j=0;j<4;j++)
        bfr[j] = *(const bf16x8*)&Bs[(wn*64 + j*16 + row)*64 + (ks*4 + k8)*8];
#pragma unroll
      for (int i=0;i<4;i++)
#pragma unroll
        for (int j=0;j<4;j++)
          acc[i][j] = __builtin_amdgcn_mfma_f32_16x16x32_bf16(af[i], bfr[j], acc[i][j], 0,0,0);
    }
  }

  // C layout per 16x16 tile: col = lane&15, row = (lane>>4)*4 + r  [m89/m91]
#pragma unroll
  for (int i=0;i<4;i++) {
    const long t = m0 + wm*64 + i*16 + (lane>>4)*4;
#pragma unroll
    for (int j=0;j<4;j++) {
      const int cj = n0 + wn*64 + j*16 + (lane&15);
      const float bv = bias[cj];
      if (EPI == 1) {
        const int sec = cj >> 8;       // 0:q 1:k 2:v 3:o (uniform per block)
        const int c   = cj & 255;
#pragma unroll
        for (int r=0;r<4;r++) {
          const long tt = t + r;
          float v = acc[i][j][r] + bv;
          if (sec < 2) v = (v > 0.f) ? (v + 1.f) : __expf(v);   // elu(v)+1
          if (sec == 1) {
            // head-major: kh_t[((b*8+h)*8192 + n)*32 + d]
            const long bh = (tt >> 13)*8 + (c >> 5);
            o1[(bh*8192 + (tt & 8191))*32 + (c & 31)] = (__bf16)v;
          } else {
            __bf16* dst = (sec==0)?(__bf16*)o0:(sec==2)?o2:o3;
            dst[tt*256 + c] = (__bf16)v;
          }
        }
      } else {
#pragma unroll
        for (int r=0;r<4;r++)
          o0[(t+r)*256 + cj] = (TO)(acc[i][j][r] + bv);
      }
    }
  }
}

// ---------------- reduce: ksum, vsum, kvT[e][d] per (b,h) --------------------
// grid (32 bh, 16 chunks of 512 tokens), 256 thr. kvT[e*32+d] = sum_n ks[n,d]v[n,e]
__global__ __launch_bounds__(256)
void reduce_kernel(const __bf16* __restrict__ kh_t, const __bf16* __restrict__ vv,
                   const float* __restrict__ sing, const float* __restrict__ cosg,
                   float* __restrict__ ksum, float* __restrict__ vsum,
                   float* __restrict__ kvT)
{
  __shared__ __align__(16) float ks_s[128*36];   // pad 36: conflict-free reads
  __shared__ __align__(16) float v_s[128*36];
  __shared__ float ksum_s[32], vsum_s[32];
  __shared__ float kvacc[1024];
  const int tid = threadIdx.x, lane = tid & 63, wid = tid >> 6;
  const int bh = blockIdx.x;             // b*8+h
  const int b = bh >> 3, h = bh & 7;
  const int n0 = blockIdx.y * 512;
  const int seg = tid & 3;               // 8-channel segment
  const int tksl = tid >> 2;             // token slot (0..63)

  if (tid < 32) { ksum_s[tid] = 0.f; vsum_s[tid] = 0.f; }
  for (int i = tid; i < 1024; i += 256) kvacc[i] = 0.f;

  float sk[8] = {}, sv[8] = {};
  f32x4 a0={},a1={},a2={},a3={};
  const int db = (lane>>3)*4, eb = (lane&7)*4;

  for (int sub = 0; sub < 4; sub++) {
    const int nbase = n0 + sub*128;
    __syncthreads();   // init visible (sub=0); prior sub's reads done (sub>0)
#pragma unroll
    for (int i=0;i<2;i++) {
      const int tok = i*64 + tksl;
      const int n = nbase + tok;
      bf16x8 k8 = *(const bf16x8*)&kh_t[((long)bh*8192 + n)*32 + seg*8];
      bf16x8 w8 = *(const bf16x8*)&vv[((long)b*8192 + n)*256 + h*32 + seg*8];
      f32x4 cA = *(const f32x4*)&cosg[n*32 + seg*8];
      f32x4 cB = *(const f32x4*)&cosg[n*32 + seg*8 + 4];
      f32x4 sA = *(const f32x4*)&sing[n*32 + seg*8];
      f32x4 sB = *(const f32x4*)&sing[n*32 + seg*8 + 4];
      float kf[8], wf[8], cf[8], sf[8], ks[8];
#pragma unroll
      for (int j=0;j<8;j++) { kf[j]=(float)k8[j]; wf[j]=(float)w8[j]; }
      cf[0]=cA.x;cf[1]=cA.y;cf[2]=cA.z;cf[3]=cA.w;cf[4]=cB.x;cf[5]=cB.y;cf[6]=cB.z;cf[7]=cB.w;
      sf[0]=sA.x;sf[1]=sA.y;sf[2]=sA.z;sf[3]=sA.w;sf[4]=sB.x;sf[5]=sB.y;sf[6]=sB.z;sf[7]=sB.w;
#pragma unroll
      for (int j=0;j<8;j+=2) {
        ks[j]   = kf[j]*cf[j]     - kf[j+1]*sf[j];     // theta_shift even
        ks[j+1] = kf[j+1]*cf[j+1] + kf[j]*sf[j+1];     // theta_shift odd
      }
      f32x4 q0 = {ks[0],ks[1],ks[2],ks[3]}, q1 = {ks[4],ks[5],ks[6],ks[7]};
      *(f32x4*)&ks_s[tok*36 + seg*8]     = q0;
      *(f32x4*)&ks_s[tok*36 + seg*8 + 4] = q1;
      f32x4 p0 = {wf[0],wf[1],wf[2],wf[3]}, p1 = {wf[4],wf[5],wf[6],wf[7]};
      *(f32x4*)&v_s[tok*36 + seg*8]     = p0;
      *(f32x4*)&v_s[tok*36 + seg*8 + 4] = p1;
#pragma unroll
      for (int j=0;j<8;j++) { sk[j] += kf[j]; sv[j] += wf[j]; }
    }
    __syncthreads();
    // wave outer product over its 32 tokens; lane owns 4x4 (d,e) block
    for (int t2 = 0; t2 < 32; t2++) {
      const int nl = wid*32 + t2;
      f32x4 kk = *(const f32x4*)&ks_s[nl*36 + db];
      f32x4 vp = *(const f32x4*)&v_s[nl*36 + eb];
      a0 += kk.x * vp;  a1 += kk.y * vp;  a2 += kk.z * vp;  a3 += kk.w * vp;
    }
  }

  // kv merge (4-way wave contention only)
#pragma unroll
  for (int e=0;e<4;e++) {
    atomicAdd(&kvacc[(eb+e)*32 + db+0], a0[e]);
    atomicAdd(&kvacc[(eb+e)*32 + db+1], a1[e]);
    atomicAdd(&kvacc[(eb+e)*32 + db+2], a2[e]);
    atomicAdd(&kvacc[(eb+e)*32 + db+3], a3[e]);
  }
  // ksum/vsum: shfl over lanes sharing seg (=lane&3), then 1 atomic per wave
#pragma unroll
  for (int m = 4; m <= 32; m <<= 1) {
#pragma unroll
    for (int j=0;j<8;j++) { sk[j] += __shfl_xor(sk[j], m); sv[j] += __shfl_xor(sv[j], m); }
  }
  if (lane < 4) {
#pragma unroll
    for (int j=0;j<8;j++) {
      atomicAdd(&ksum_s[lane*8 + j], sk[j]);
      atomicAdd(&vsum_s[lane*8 + j], sv[j]);
    }
  }
  __syncthreads();
  float* dst = kvT + (long)bh*1024;
  for (int i = tid; i < 1024; i += 256) atomicAdd(&dst[i], kvacc[i]);
  if (tid < 32) { atomicAdd(&ksum[bh*32+tid], ksum_s[tid]);
                  atomicAdd(&vsum[bh*32+tid], vsum_s[tid]); }
}

// ---------------- epilogue: qs, z, attn (MFMA), MALA, lepe, *o --------------
// grid 1024 blocks x 32 tokens, 256 threads. resf = xbf buffer (dead after
// gemm1); no alias with any pointer read here.
__global__ __launch_bounds__(256)
void epi_kernel(const __bf16* __restrict__ qh, const __bf16* __restrict__ vv,
                const __bf16* __restrict__ oo,
                const float* __restrict__ sing, const float* __restrict__ cosg,
                const float* __restrict__ ksum, const float* __restrict__ vsum,
                const float* __restrict__ kvT,
                const float* __restrict__ Wl, const float* __restrict__ bl,
                __bf16* __restrict__ resf)
{
  __shared__ __align__(16) __bf16 qs_s[32*256];     // [t][c]
  __shared__ __align__(16) __bf16 kv_s[8*32*32];    // [h][e][d] (B-frag source)
  __shared__ __align__(16) __bf16 lep_s[32*256];
  __shared__ float z_s[32*8];
  __shared__ float km_s[256], vm_s[256];
  const int tid = threadIdx.x, lane = tid & 63, wid = tid >> 6;
  const long t0 = (long)blockIdx.x * 32;
  const int b  = (int)(t0 >> 13);
  const int n0 = (int)(t0 & 8191);
  const int bh0 = b * 8;

  for (int i = tid; i < 8192; i += 256)
    kv_s[i] = (__bf16)(kvT[(long)bh0*1024 + i] * S2_F);
  km_s[tid] = ksum[bh0*32 + tid] * (1.f/8192.f);
  vm_s[tid] = vsum[bh0*32 + tid] * (1.f/8192.f);
  __syncthreads();

  // qs + z
  for (int i=0;i<16;i++) {
    const int p  = i*256 + tid;
    const int t  = p >> 7;
    const int c2 = p & 127;
    const int h  = c2 >> 4;
    const int d0 = (c2 & 15) * 2;
    const long tg = t0 + t;
    const int n = n0 + t;
    const float q0 = (float)qh[tg*256 + h*32 + d0];
    const float q1 = (float)qh[tg*256 + h*32 + d0 + 1];
    f32x2 cp = *(const f32x2*)&cosg[n*32 + d0];
    f32x2 sp = *(const f32x2*)&sing[n*32 + d0];
    qs_s[t*256 + h*32 + d0]     = (__bf16)(q0*cp.x - q1*sp.x);
    qs_s[t*256 + h*32 + d0 + 1] = (__bf16)(q1*cp.y + q0*sp.y);
    float zp = q0*km_s[h*32+d0] + q1*km_s[h*32+d0+1];
    zp += __shfl_xor(zp, 1);
    zp += __shfl_xor(zp, 2);
    zp += __shfl_xor(zp, 4);
    zp += __shfl_xor(zp, 8);
    if ((lane & 15) == 0) z_s[t*8 + h] = zp * SCALE_F;
  }
  // lepe depthwise conv k=3 (zero pad at per-batch sequence ends)
  for (int i=0;i<32;i++) {
    const int f = i*256 + tid;
    const int t = f >> 8;
    const int c = f & 255;
    const long tg = t0 + t;
    const int n = n0 + t;
    const float vm1 = (n > 0)      ? (float)vv[(tg-1)*256 + c] : 0.f;
    const float v0  =                (float)vv[tg*256 + c];
    const float vp1 = (n < NSEQ-1) ? (float)vv[(tg+1)*256 + c] : 0.f;
    lep_s[f] = (__bf16)(vm1*Wl[c*3+0] + v0*Wl[c*3+1] + vp1*Wl[c*3+2] + bl[c]);
  }
  __syncthreads();

  const int e  = lane & 15;
  const int d8 = (lane >> 4) * 8;
  for (int hh=0; hh<2; hh++) {
    const int h = wid*2 + hh;
    bf16x8 bfr0 = *(const bf16x8*)&kv_s[h*1024 + e*32 + d8];
    bf16x8 bfr1 = *(const bf16x8*)&kv_s[h*1024 + (16+e)*32 + d8];
    for (int im=0; im<2; im++) {
      bf16x8 afr = *(const bf16x8*)&qs_s[(im*16 + e)*256 + h*32 + d8];
      for (int jn=0; jn<2; jn++) {
        f32x4 acc = {};
        acc = __builtin_amdgcn_mfma_f32_16x16x32_bf16(afr, jn ? bfr1 : bfr0, acc, 0,0,0);
        const int c = h*32 + jn*16 + e;
        const float vmn = vm_s[c];
#pragma unroll
        for (int r=0;r<4;r++) {
          const int t = im*16 + (lane>>4)*4 + r;
          const long tg = t0 + t;
          const float zv = z_s[t*8 + h];
          const float res = acc[r]*(1.f + 1.f/(zv + 1e-6f)) - zv*vmn
                            + (float)lep_s[t*256 + c];
          resf[tg*256 + c] = (__bf16)(res * (float)oo[tg*256 + c]);
        }
      }
    }
  }
}

// ---------------------------------------------------------------------------
extern "C" void kernel_launch(void* const* d_in, const int* in_sizes, int n_in,
                              void* d_out, int out_size, void* d_ws, size_t ws_size,
                              hipStream_t stream)
{
  const float* x    = (const float*)d_in[0];
  const float* sing = (const float*)d_in[1];
  const float* cosg = (const float*)d_in[2];
  const float* Wq   = (const float*)d_in[3];
  const float* bq   = (const float*)d_in[4];
  const float* Wl   = (const float*)d_in[5];
  const float* bl   = (const float*)d_in[6];
  const float* Wp   = (const float*)d_in[7];
  const float* bp   = (const float*)d_in[8];
  float* out = (float*)d_out;

  char* ws = (char*)d_ws;
  float*  ksum = (float*)(ws);
  float*  vsum = (float*)(ws + 4096);
  float*  kvT  = (float*)(ws + 8192);
  const size_t T0 = 256 * 1024;
  const size_t SZ = (size_t)TOK * 256 * sizeof(__bf16);  // 16 MB
  __bf16* kh_t = (__bf16*)(ws + T0);
  __bf16* vv   = (__bf16*)(ws + T0 + SZ);
  __bf16* oo   = (__bf16*)(ws + T0 + 2*SZ);
  __bf16* qh   = (__bf16*)(ws + T0 + 3*SZ);
  __bf16* xbf  = (__bf16*)(ws + T0 + 4*SZ);
  __bf16* Wqb  = (__bf16*)(ws + T0 + 5*SZ);
  __bf16* Wpb  = (__bf16*)(ws + T0 + 5*SZ + 512*1024);
  __bf16* resf = xbf;   // xbf dead after gemm1; epi/gemm2 never read xbf

  hipMemsetAsync(ws, 0, 8192 + 32*1024*4, stream);

  cvt_kernel<<<4096, 256, 0, stream>>>(x,  xbf, TOK*256/8);
  cvt_kernel<<<128,  256, 0, stream>>>(Wq, Wqb, 1024*256/8);
  cvt_kernel<<<32,   256, 0, stream>>>(Wp, Wpb, 256*256/8);

  gemm_kernel<1,__bf16><<<dim3(256, 8), 256, 0, stream>>>(xbf, Wqb, bq, qh, kh_t, vv, oo);
  reduce_kernel<<<dim3(32, 16), 256, 0, stream>>>(kh_t, vv, sing, cosg, ksum, vsum, kvT);
  epi_kernel<<<1024, 256, 0, stream>>>(qh, vv, oo, sing, cosg, ksum, vsum, kvT, Wl, bl, resf);
  gemm_kernel<2,float><<<dim3(256, 2), 256, 0, stream>>>(resf, Wpb, bp, out, nullptr, nullptr, nullptr);
}

// Round 10
// 201.425 us; speedup vs baseline: 1.0600x; 1.0600x over previous
//
#include <hip/hip_runtime.h>
#include <hip/hip_bf16.h>

// MultiHeadMALAAttention: B=4 N=8192 DIM=256 H=8 HD=32 INTERNAL=256
// Dtypes: inputs fp32, output fp32; intermediates bf16; compute fp32.
// R10: epi_kernel vectorized (was scalar 2B loads: 96/thread in lepe loop —
// same latency disease as R5's reduce). GEMM/reduce byte-identical to R9
// (proven). XOR swizzle permanently abandoned (R8 post-timing corruption).
// ws (~81 MB): [0,4K) ksum | [4K,8K) vsum | [8K,136K) kvT | 256K: kh_t vv oo
// qh xbf (16MB each) | Wqb | Wpb. resf aliases xbf (dead after gemm1).

typedef __bf16 bf16x8 __attribute__((ext_vector_type(8)));
typedef float  f32x4  __attribute__((ext_vector_type(4)));
typedef float  f32x2  __attribute__((ext_vector_type(2)));

#define NSEQ  8192
#define TOK   32768
#define SCALE_F 0.17677669529663687f        // 32^-0.5
#define S2_F    2.1579674718339462e-05f     // SCALE/NSEQ

__device__ __forceinline__ void gld16(void* lds, const void* g) {
  __builtin_amdgcn_global_load_lds((const __attribute__((address_space(1))) void*)g,
                                   (__attribute__((address_space(3))) void*)lds,
                                   16, 0, 0);
}

__device__ __forceinline__ bf16x8 cvt8(const float* p) {
  f32x4 a = *(const f32x4*)p;
  f32x4 b = *(const f32x4*)(p + 4);
  bf16x8 r;
  r[0]=(__bf16)a.x; r[1]=(__bf16)a.y; r[2]=(__bf16)a.z; r[3]=(__bf16)a.w;
  r[4]=(__bf16)b.x; r[5]=(__bf16)b.y; r[6]=(__bf16)b.z; r[7]=(__bf16)b.w;
  return r;
}

// ---------------- cvt: fp32 -> bf16, 8 elems/thread --------------------------
__global__ __launch_bounds__(256)
void cvt_kernel(const float* __restrict__ src, __bf16* __restrict__ dst, int n8)
{
  const int i = blockIdx.x*256 + threadIdx.x;
  if (i >= n8) return;
  *(bf16x8*)(dst + (long)i*8) = cvt8(src + (long)i*8);
}

// ---------------- GEMM: C[M x Nn] = A[M x K] * B[Nn x K]^T, K=256 ------------
// 128x128 tile, BK=64, global_load_lds(16B) staging (identity addressing),
// 4 waves, each wave 4x4 16x16x32 MFMA tiles (2 k-steps/iter). [R9-proven]
template<int EPI, typename TO>
__global__ __launch_bounds__(256)
void gemm_kernel(const __bf16* __restrict__ A, const __bf16* __restrict__ Bw,
                 const float* __restrict__ bias,
                 TO* __restrict__ o0, __bf16* __restrict__ o1,
                 __bf16* __restrict__ o2, __bf16* __restrict__ o3)
{
  constexpr int K = 256;
  __shared__ __align__(16) __bf16 As[128*64];   // 16 KB
  __shared__ __align__(16) __bf16 Bs[128*64];   // 16 KB
  const int tid  = threadIdx.x;
  const int lane = tid & 63;
  const int wid  = tid >> 6;
  const int wm = wid & 1, wn = wid >> 1;
  const long m0 = (long)blockIdx.x * 128;
  const int  n0 = blockIdx.y * 128;

  const int srow = tid >> 3;                 // 0..31 (staging row within call)
  const int scol = tid & 7;                  // col8 slot (identity mapping)
  const __bf16* ag = A  + (m0 + srow)*K + scol*8;
  const __bf16* bg = Bw + (long)(n0 + srow)*K + scol*8;
  __bf16* asw = As + tid*8;                  // lane-contig 16B (gld16 dst rule)
  __bf16* bsw = Bs + tid*8;

  f32x4 acc[4][4] = {};

  for (int k0 = 0; k0 < K; k0 += 64) {
    __syncthreads();                       // prior iter's ds_reads complete
#pragma unroll
    for (int q = 0; q < 4; q++) {          // call q covers rows q*32..q*32+31
      gld16(asw + q*2048, ag + (long)q*32*K + k0);
      gld16(bsw + q*2048, bg + (long)q*32*K + k0);
    }
    __syncthreads();                       // staging visible (vmcnt drain)
    const int row = lane & 15;
    const int k8  = lane >> 4;             // 0..3
#pragma unroll
    for (int ks = 0; ks < 2; ks++) {
      bf16x8 af[4], bfr[4];
#pragma unroll
      for (int i=0;i<4;i++)
        af[i] = *(const bf16x8*)&As[(wm*64 + i*16 + row)*64 + (ks*4 + k8)*8];
#pragma unroll
      for (int j=0;j<4;j++)
        bfr[j] = *(const bf16x8*)&Bs[(wn*64 + j*16 + row)*64 + (ks*4 + k8)*8];
#pragma unroll
      for (int i=0;i<4;i++)
#pragma unroll
        for (int j=0;j<4;j++)
          acc[i][j] = __builtin_amdgcn_mfma_f32_16x16x32_bf16(af[i], bfr[j], acc[i][j], 0,0,0);
    }
  }

  // C layout per 16x16 tile: col = lane&15, row = (lane>>4)*4 + r  [m89/m91]
#pragma unroll
  for (int i=0;i<4;i++) {
    const long t = m0 + wm*64 + i*16 + (lane>>4)*4;
#pragma unroll
    for (int j=0;j<4;j++) {
      const int cj = n0 + wn*64 + j*16 + (lane&15);
      const float bv = bias[cj];
      if (EPI == 1) {
        const int sec = cj >> 8;       // 0:q 1:k 2:v 3:o (uniform per block)
        const int c   = cj & 255;
#pragma unroll
        for (int r=0;r<4;r++) {
          const long tt = t + r;
          float v = acc[i][j][r] + bv;
          if (sec < 2) v = (v > 0.f) ? (v + 1.f) : __expf(v);   // elu(v)+1
          if (sec == 1) {
            // head-major: kh_t[((b*8+h)*8192 + n)*32 + d]
            const long bh = (tt >> 13)*8 + (c >> 5);
            o1[(bh*8192 + (tt & 8191))*32 + (c & 31)] = (__bf16)v;
          } else {
            __bf16* dst = (sec==0)?(__bf16*)o0:(sec==2)?o2:o3;
            dst[tt*256 + c] = (__bf16)v;
          }
        }
      } else {
#pragma unroll
        for (int r=0;r<4;r++)
          o0[(t+r)*256 + cj] = (TO)(acc[i][j][r] + bv);
      }
    }
  }
}

// ---------------- reduce: ksum, vsum, kvT[e][d] per (b,h) --------------------
// grid (32 bh, 16 chunks of 512 tokens), 256 thr. [R6-proven, unchanged]
__global__ __launch_bounds__(256)
void reduce_kernel(const __bf16* __restrict__ kh_t, const __bf16* __restrict__ vv,
                   const float* __restrict__ sing, const float* __restrict__ cosg,
                   float* __restrict__ ksum, float* __restrict__ vsum,
                   float* __restrict__ kvT)
{
  __shared__ __align__(16) float ks_s[128*36];   // pad 36: conflict-free reads
  __shared__ __align__(16) float v_s[128*36];
  __shared__ float ksum_s[32], vsum_s[32];
  __shared__ float kvacc[1024];
  const int tid = threadIdx.x, lane = tid & 63, wid = tid >> 6;
  const int bh = blockIdx.x;             // b*8+h
  const int b = bh >> 3, h = bh & 7;
  const int n0 = blockIdx.y * 512;
  const int seg = tid & 3;               // 8-channel segment
  const int tksl = tid >> 2;             // token slot (0..63)

  if (tid < 32) { ksum_s[tid] = 0.f; vsum_s[tid] = 0.f; }
  for (int i = tid; i < 1024; i += 256) kvacc[i] = 0.f;

  float sk[8] = {}, sv[8] = {};
  f32x4 a0={},a1={},a2={},a3={};
  const int db = (lane>>3)*4, eb = (lane&7)*4;

  for (int sub = 0; sub < 4; sub++) {
    const int nbase = n0 + sub*128;
    __syncthreads();   // init visible (sub=0); prior sub's reads done (sub>0)
#pragma unroll
    for (int i=0;i<2;i++) {
      const int tok = i*64 + tksl;
      const int n = nbase + tok;
      bf16x8 k8 = *(const bf16x8*)&kh_t[((long)bh*8192 + n)*32 + seg*8];
      bf16x8 w8 = *(const bf16x8*)&vv[((long)b*8192 + n)*256 + h*32 + seg*8];
      f32x4 cA = *(const f32x4*)&cosg[n*32 + seg*8];
      f32x4 cB = *(const f32x4*)&cosg[n*32 + seg*8 + 4];
      f32x4 sA = *(const f32x4*)&sing[n*32 + seg*8];
      f32x4 sB = *(const f32x4*)&sing[n*32 + seg*8 + 4];
      float kf[8], wf[8], cf[8], sf[8], ks[8];
#pragma unroll
      for (int j=0;j<8;j++) { kf[j]=(float)k8[j]; wf[j]=(float)w8[j]; }
      cf[0]=cA.x;cf[1]=cA.y;cf[2]=cA.z;cf[3]=cA.w;cf[4]=cB.x;cf[5]=cB.y;cf[6]=cB.z;cf[7]=cB.w;
      sf[0]=sA.x;sf[1]=sA.y;sf[2]=sA.z;sf[3]=sA.w;sf[4]=sB.x;sf[5]=sB.y;sf[6]=sB.z;sf[7]=sB.w;
#pragma unroll
      for (int j=0;j<8;j+=2) {
        ks[j]   = kf[j]*cf[j]     - kf[j+1]*sf[j];     // theta_shift even
        ks[j+1] = kf[j+1]*cf[j+1] + kf[j]*sf[j+1];     // theta_shift odd
      }
      f32x4 q0 = {ks[0],ks[1],ks[2],ks[3]}, q1 = {ks[4],ks[5],ks[6],ks[7]};
      *(f32x4*)&ks_s[tok*36 + seg*8]     = q0;
      *(f32x4*)&ks_s[tok*36 + seg*8 + 4] = q1;
      f32x4 p0 = {wf[0],wf[1],wf[2],wf[3]}, p1 = {wf[4],wf[5],wf[6],wf[7]};
      *(f32x4*)&v_s[tok*36 + seg*8]     = p0;
      *(f32x4*)&v_s[tok*36 + seg*8 + 4] = p1;
#pragma unroll
      for (int j=0;j<8;j++) { sk[j] += kf[j]; sv[j] += wf[j]; }
    }
    __syncthreads();
    // wave outer product over its 32 tokens; lane owns 4x4 (d,e) block
    for (int t2 = 0; t2 < 32; t2++) {
      const int nl = wid*32 + t2;
      f32x4 kk = *(const f32x4*)&ks_s[nl*36 + db];
      f32x4 vp = *(const f32x4*)&v_s[nl*36 + eb];
      a0 += kk.x * vp;  a1 += kk.y * vp;  a2 += kk.z * vp;  a3 += kk.w * vp;
    }
  }

  // kv merge (4-way wave contention only)
#pragma unroll
  for (int e=0;e<4;e++) {
    atomicAdd(&kvacc[(eb+e)*32 + db+0], a0[e]);
    atomicAdd(&kvacc[(eb+e)*32 + db+1], a1[e]);
    atomicAdd(&kvacc[(eb+e)*32 + db+2], a2[e]);
    atomicAdd(&kvacc[(eb+e)*32 + db+3], a3[e]);
  }
  // ksum/vsum: shfl over lanes sharing seg (=lane&3), then 1 atomic per wave
#pragma unroll
  for (int m = 4; m <= 32; m <<= 1) {
#pragma unroll
    for (int j=0;j<8;j++) { sk[j] += __shfl_xor(sk[j], m); sv[j] += __shfl_xor(sv[j], m); }
  }
  if (lane < 4) {
#pragma unroll
    for (int j=0;j<8;j++) {
      atomicAdd(&ksum_s[lane*8 + j], sk[j]);
      atomicAdd(&vsum_s[lane*8 + j], sv[j]);
    }
  }
  __syncthreads();
  float* dst = kvT + (long)bh*1024;
  for (int i = tid; i < 1024; i += 256) atomicAdd(&dst[i], kvacc[i]);
  if (tid < 32) { atomicAdd(&ksum[bh*32+tid], ksum_s[tid]);
                  atomicAdd(&vsum[bh*32+tid], vsum_s[tid]); }
}

// ---------------- epilogue: qs, z, attn (MFMA), MALA, lepe, *o --------------
// grid 1024 blocks x 32 tokens, 256 threads. R10: fully vectorized prep loops
// (bf16x8 / f32x4), 8 channels/thread, 4 passes each. resf = xbf (dead).
__global__ __launch_bounds__(256)
void epi_kernel(const __bf16* __restrict__ qh, const __bf16* __restrict__ vv,
                const __bf16* __restrict__ oo,
                const float* __restrict__ sing, const float* __restrict__ cosg,
                const float* __restrict__ ksum, const float* __restrict__ vsum,
                const float* __restrict__ kvT,
                const float* __restrict__ Wl, const float* __restrict__ bl,
                __bf16* __restrict__ resf)
{
  __shared__ __align__(16) __bf16 qs_s[32*256];     // [t][c]
  __shared__ __align__(16) __bf16 kv_s[8*32*32];    // [h][e][d] (B-frag source)
  __shared__ __align__(16) __bf16 lep_s[32*256];
  __shared__ float z_s[32*8];
  __shared__ __align__(16) float km_s[256], vm_s[256];
  const int tid = threadIdx.x, lane = tid & 63, wid = tid >> 6;
  const long t0 = (long)blockIdx.x * 32;
  const int b  = (int)(t0 >> 13);
  const int n0 = (int)(t0 & 8191);
  const int bh0 = b * 8;

  for (int i = tid; i < 8192; i += 256)
    kv_s[i] = (__bf16)(kvT[(long)bh0*1024 + i] * S2_F);
  km_s[tid] = ksum[bh0*32 + tid] * (1.f/8192.f);
  vm_s[tid] = vsum[bh0*32 + tid] * (1.f/8192.f);
  __syncthreads();

  // qs + z: 4 passes, thread = (t = pass*8 + tid>>5, 8 channels c = (tid&31)*8)
#pragma unroll
  for (int pass=0; pass<4; pass++) {
    const int t  = pass*8 + (tid>>5);
    const int c  = (tid & 31) * 8;
    const int d  = c & 31;                  // rope depends on d = c mod 32
    const int h  = c >> 5;
    const long tg = t0 + t;
    const int n = n0 + t;
    bf16x8 q8 = *(const bf16x8*)&qh[tg*256 + c];
    f32x4 cA = *(const f32x4*)&cosg[n*32 + d];
    f32x4 cB = *(const f32x4*)&cosg[n*32 + d + 4];
    f32x4 sA = *(const f32x4*)&sing[n*32 + d];
    f32x4 sB = *(const f32x4*)&sing[n*32 + d + 4];
    f32x4 kmA = *(const f32x4*)&km_s[c];
    f32x4 kmB = *(const f32x4*)&km_s[c + 4];
    float qf[8], cf[8], sf[8], kmf[8];
#pragma unroll
    for (int j=0;j<8;j++) qf[j] = (float)q8[j];
    cf[0]=cA.x;cf[1]=cA.y;cf[2]=cA.z;cf[3]=cA.w;cf[4]=cB.x;cf[5]=cB.y;cf[6]=cB.z;cf[7]=cB.w;
    sf[0]=sA.x;sf[1]=sA.y;sf[2]=sA.z;sf[3]=sA.w;sf[4]=sB.x;sf[5]=sB.y;sf[6]=sB.z;sf[7]=sB.w;
    kmf[0]=kmA.x;kmf[1]=kmA.y;kmf[2]=kmA.z;kmf[3]=kmA.w;
    kmf[4]=kmB.x;kmf[5]=kmB.y;kmf[6]=kmB.z;kmf[7]=kmB.w;
    bf16x8 qs8;
    float zp = 0.f;
#pragma unroll
    for (int j=0;j<8;j+=2) {
      qs8[j]   = (__bf16)(qf[j]*cf[j]     - qf[j+1]*sf[j]);
      qs8[j+1] = (__bf16)(qf[j+1]*cf[j+1] + qf[j]*sf[j+1]);
      zp += qf[j]*kmf[j] + qf[j+1]*kmf[j+1];
    }
    *(bf16x8*)&qs_s[t*256 + c] = qs8;
    zp += __shfl_xor(zp, 1);
    zp += __shfl_xor(zp, 2);               // sum over 4 lanes sharing (t,h)
    if ((lane & 3) == 0) z_s[t*8 + h] = zp * SCALE_F;
  }

  // lepe: 4 passes, 8 channels/thread, vectorized loads (rows L2-hot)
#pragma unroll
  for (int pass=0; pass<4; pass++) {
    const int t = pass*8 + (tid>>5);
    const int c = (tid & 31) * 8;
    const long tg = t0 + t;
    const int n = n0 + t;
    bf16x8 v0 = *(const bf16x8*)&vv[tg*256 + c];
    bf16x8 vm1, vp1;
#pragma unroll
    for (int j=0;j<8;j++) { vm1[j] = (__bf16)0.f; vp1[j] = (__bf16)0.f; }
    if (n > 0)      vm1 = *(const bf16x8*)&vv[(tg-1)*256 + c];
    if (n < NSEQ-1) vp1 = *(const bf16x8*)&vv[(tg+1)*256 + c];
    float wf[24], bf[8];
#pragma unroll
    for (int q=0;q<6;q++) {
      f32x4 w = *(const f32x4*)&Wl[c*3 + q*4];
      wf[q*4+0]=w.x; wf[q*4+1]=w.y; wf[q*4+2]=w.z; wf[q*4+3]=w.w;
    }
    { f32x4 b0 = *(const f32x4*)&bl[c];  f32x4 b1 = *(const f32x4*)&bl[c+4];
      bf[0]=b0.x;bf[1]=b0.y;bf[2]=b0.z;bf[3]=b0.w;bf[4]=b1.x;bf[5]=b1.y;bf[6]=b1.z;bf[7]=b1.w; }
    bf16x8 lp;
#pragma unroll
    for (int j=0;j<8;j++)
      lp[j] = (__bf16)((float)vm1[j]*wf[j*3] + (float)v0[j]*wf[j*3+1]
                       + (float)vp1[j]*wf[j*3+2] + bf[j]);
    *(bf16x8*)&lep_s[t*256 + c] = lp;
  }
  __syncthreads();

  const int e  = lane & 15;
  const int d8 = (lane >> 4) * 8;
  for (int hh=0; hh<2; hh++) {
    const int h = wid*2 + hh;
    bf16x8 bfr0 = *(const bf16x8*)&kv_s[h*1024 + e*32 + d8];
    bf16x8 bfr1 = *(const bf16x8*)&kv_s[h*1024 + (16+e)*32 + d8];
    for (int im=0; im<2; im++) {
      bf16x8 afr = *(const bf16x8*)&qs_s[(im*16 + e)*256 + h*32 + d8];
      for (int jn=0; jn<2; jn++) {
        f32x4 acc = {};
        acc = __builtin_amdgcn_mfma_f32_16x16x32_bf16(afr, jn ? bfr1 : bfr0, acc, 0,0,0);
        const int c = h*32 + jn*16 + e;
        const float vmn = vm_s[c];
#pragma unroll
        for (int r=0;r<4;r++) {
          const int t = im*16 + (lane>>4)*4 + r;
          const long tg = t0 + t;
          const float zv = z_s[t*8 + h];
          const float res = acc[r]*(1.f + 1.f/(zv + 1e-6f)) - zv*vmn
                            + (float)lep_s[t*256 + c];
          resf[tg*256 + c] = (__bf16)(res * (float)oo[tg*256 + c]);
        }
      }
    }
  }
}

// ---------------------------------------------------------------------------
extern "C" void kernel_launch(void* const* d_in, const int* in_sizes, int n_in,
                              void* d_out, int out_size, void* d_ws, size_t ws_size,
                              hipStream_t stream)
{
  const float* x    = (const float*)d_in[0];
  const float* sing = (const float*)d_in[1];
  const float* cosg = (const float*)d_in[2];
  const float* Wq   = (const float*)d_in[3];
  const float* bq   = (const float*)d_in[4];
  const float* Wl   = (const float*)d_in[5];
  const float* bl   = (const float*)d_in[6];
  const float* Wp   = (const float*)d_in[7];
  const float* bp   = (const float*)d_in[8];
  float* out = (float*)d_out;

  char* ws = (char*)d_ws;
  float*  ksum = (float*)(ws);
  float*  vsum = (float*)(ws + 4096);
  float*  kvT  = (float*)(ws + 8192);
  const size_t T0 = 256 * 1024;
  const size_t SZ = (size_t)TOK * 256 * sizeof(__bf16);  // 16 MB
  __bf16* kh_t = (__bf16*)(ws + T0);
  __bf16* vv   = (__bf16*)(ws + T0 + SZ);
  __bf16* oo   = (__bf16*)(ws + T0 + 2*SZ);
  __bf16* qh   = (__bf16*)(ws + T0 + 3*SZ);
  __bf16* xbf  = (__bf16*)(ws + T0 + 4*SZ);
  __bf16* Wqb  = (__bf16*)(ws + T0 + 5*SZ);
  __bf16* Wpb  = (__bf16*)(ws + T0 + 5*SZ + 512*1024);
  __bf16* resf = xbf;   // xbf dead after gemm1; epi/gemm2 never read xbf

  hipMemsetAsync(ws, 0, 8192 + 32*1024*4, stream);

  cvt_kernel<<<4096, 256, 0, stream>>>(x,  xbf, TOK*256/8);
  cvt_kernel<<<128,  256, 0, stream>>>(Wq, Wqb, 1024*256/8);
  cvt_kernel<<<32,   256, 0, stream>>>(Wp, Wpb, 256*256/8);

  gemm_kernel<1,__bf16><<<dim3(256, 8), 256, 0, stream>>>(xbf, Wqb, bq, qh, kh_t, vv, oo);
  reduce_kernel<<<dim3(32, 16), 256, 0, stream>>>(kh_t, vv, sing, cosg, ksum, vsum, kvT);
  epi_kernel<<<1024, 256, 0, stream>>>(qh, vv, oo, sing, cosg, ksum, vsum, kvT, Wl, bl, resf);
  gemm_kernel<2,float><<<dim3(256, 2), 256, 0, stream>>>(resf, Wpb, bp, out, nullptr, nullptr, nullptr);
}